// Round 19
// baseline (1901.848 us; speedup 1.0000x reference)
//
#include <hip/hip_runtime.h>
#include <hip/hip_bf16.h>

#define BDIM 64
#define TDIM 360
#define BT (BDIM*TDIM)        // 23040
#define CDIM 128
#define HWSZ 1024
#define SDIM 64
#define G4 512
#define KTOP 160

typedef __hip_bfloat16 bf16;
typedef __fp16 h2 __attribute__((ext_vector_type(2)));   // cvt_pkrtz/fdot2 native type

static __device__ __forceinline__ unsigned int f2bu(float x) {
    bf16 b = __float2bfloat16(x);
    unsigned short u; __builtin_memcpy(&u, &b, 2); return (unsigned int)u;
}
static __device__ __forceinline__ h2 u2h(unsigned int u) {
    h2 r; __builtin_memcpy(&r, &u, 4); return r;
}
static __device__ __forceinline__ unsigned int packh(float a, float b) {
    h2 v = __builtin_amdgcn_cvt_pkrtz(a, b);
    unsigned int u; __builtin_memcpy(&u, &v, 4); return u;
}
static __device__ __forceinline__ float fdot2(unsigned int a, unsigned int b, float c) {
    return __builtin_amdgcn_fdot2(u2h(a), u2h(b), c, false);
}
static __device__ __forceinline__ float tanh_fast(float x) {
    float e = __expf(2.0f * x);
    return 1.0f - 2.0f / (e + 1.0f);
}
static __device__ __forceinline__ float sigm(float x) {
    return 1.0f / (1.0f + __expf(-x));
}

// ---- static device workspace ----
__device__ float        g_ArowsF[BT * KTOP];   // [x_emb(32) | in_seq(128)] fp32
// pre2 stored PERMUTED: column pl = ((n&127)<<2)|(n>>7) so kC reads at +tid
__device__ float        g_pre2[BT * G4];
// folded recurrent weights (h-half), f16 PAIRS, streaming layout
__device__ __align__(16) unsigned int g_wpk2[16 * 1024 * 4];
__device__ float        g_wrecA[128 * G4];     // att-half fold, fp32 (for kA2e)
__device__ __align__(16) unsigned int g_encW2[BDIM * G4 * 32]; // encW[b][n][s2] f16-pairs
__device__ float        g_encWao[BDIM * 64 * 5];
__device__ float        g_penc[BDIM * SDIM * 64];
__device__ float        g_hw[BT * 192];        // [h(128) | wgt(64)] per (b,t)
__device__ float        g_Wao[256 * 5];
__device__ float        g_bao[5];
__device__ float        g_bias[G4];
__device__ float        g_c0[G4];

// ---- A1: build [x_emb | gathered feature] rows ----
__global__ void kA1(const float* __restrict__ tok, const float* __restrict__ feat,
                    const float* __restrict__ Wemb, const float* __restrict__ bemb) {
    int row  = blockIdx.x * 4 + (threadIdx.x >> 6);
    int lane = threadIdx.x & 63;
    const float* tp = tok + (size_t)row * 4;
    float t0 = tp[0], t1 = tp[1], t2 = tp[2], t3 = tp[3];
    int b = row / TDIM;
    int x = (int)(t0 * 100.0f);
    int y = (int)(t1 * 100.0f);
    x = min(max(x, 0), 31);
    y = min(max(y, 0), 31);
    int idx = y * 32 + x;
    float* out = g_ArowsF + (size_t)row * KTOP;
    if (lane < 32) {
        float e = t0 * Wemb[lane] + t1 * Wemb[32 + lane] +
                  t2 * Wemb[64 + lane] + t3 * Wemb[96 + lane] + bemb[lane];
        out[lane] = e;
    }
    const float* fb = feat + (size_t)b * CDIM * HWSZ + idx;
    out[32 + lane]      = fb[(size_t)lane * HWSZ];
    out[32 + 64 + lane] = fb[(size_t)(64 + lane) * HWSZ];
}

// ---- A2a: fold recurrent weights; h-half packed f16, att-half fp32 ----
__global__ void kA2a(const float* __restrict__ Wih, const float* __restrict__ Whh,
                     const float* __restrict__ Waap) {
    __shared__ float sa0[128], sa1[128];
    int p = blockIdx.x, n = threadIdx.x;
    int r0 = 2 * p, r1 = 2 * p + 1;
    if (n < 128)            sa0[n]        = Waap[r0 * 128 + n];
    else if (n < 256)       sa1[n - 128]  = Waap[r1 * 128 + (n - 128)];
    __syncthreads();
    float acc0 = (r0 < 128) ? Whh[r0 * G4 + n] : 0.0f;
    float acc1 = (r1 < 128) ? Whh[r1 * G4 + n] : 0.0f;
    for (int j = 0; j < 128; ++j) {
        float wi = Wih[(160 + j) * G4 + n];
        acc0 += sa0[j] * wi;
        acc1 += sa1[j] * wi;
    }
    int kh = p >> 6, j = p & 63;
    int jblk = j >> 2, jj = j & 3;
    int u = kh * 512 + n;
    g_wpk2[((size_t)jblk * 1024 + u) * 4 + jj] = packh(acc0, acc1);  // f16 pair
    if (p >= 64) {                         // att-half rows, fp32 for kA2e fold
        g_wrecA[(r0 - 128) * G4 + n] = acc0;
        g_wrecA[(r1 - 128) * G4 + n] = acc1;
    }
}

// ---- A2c: bias vectors, c0, Wao, bao ----
__global__ void kA2c(const float* __restrict__ bih, const float* __restrict__ bhh,
                     const float* __restrict__ Wih, const float* __restrict__ Waap,
                     const float* __restrict__ baap, const float* __restrict__ Wout,
                     const float* __restrict__ bout) {
    __shared__ float sb[128];
    int n = threadIdx.x;
    if (n < 128) sb[n] = baap[n];
    __syncthreads();
    g_bias[n] = bih[n] + bhh[n];
    float c0 = 0.0f;
    for (int j = 0; j < 128; ++j) c0 += sb[j] * Wih[(160 + j) * G4 + n];
    g_c0[n] = c0;
    if (n < 256) {
        for (int o = 0; o < 5; ++o) {
            float acc = 0.0f;
            for (int j = 0; j < 128; ++j) acc += Waap[n * 128 + j] * Wout[j * 5 + o];
            g_Wao[n * 5 + o] = acc;
        }
    }
    if (n == 0) {
        for (int o = 0; o < 5; ++o) {
            float acc = bout[o];
            for (int j = 0; j < 128; ++j) acc += sb[j] * Wout[j * 5 + o];
            g_bao[o] = acc;
        }
    }
}

// ---- A2d: p_enc ----
__global__ void kA2d(const float* __restrict__ FH, const float* __restrict__ Wep,
                     const float* __restrict__ bep) {
    __shared__ float sfh[128 * 64];
    int b = blockIdx.x, tid = threadIdx.x;
    for (int i = tid; i < 128 * 64; i += 256) sfh[i] = FH[(size_t)b * 128 * 64 + i];
    __syncthreads();
    int a = tid & 63, sg = tid >> 6;
    float bias = bep[a];
    float acc[16];
#pragma unroll
    for (int i = 0; i < 16; ++i) acc[i] = bias;
    for (int d = 0; d < 128; ++d) {
        float wa = Wep[d * 64 + a];
#pragma unroll
        for (int i = 0; i < 16; ++i) acc[i] += sfh[d * 64 + sg * 16 + i] * wa;
    }
    for (int i = 0; i < 16; ++i)
        g_penc[((size_t)b * 64 + sg * 16 + i) * 64 + a] = acc[i];
}

// ---- A2e: encW[b] = enc[b] @ Wrec_att (f16 pack), encWao[b] = enc[b] @ Wao_att ----
__global__ void kA2e(const float* __restrict__ FH) {
    __shared__ float encL[64][129];      // enc[s][d], padded
    int b = blockIdx.x, tid = threadIdx.x;
    for (int i = tid; i < 8192; i += 512) {
        int d = i >> 6, s = i & 63;
        encL[s][d] = FH[(size_t)b * 8192 + i];
    }
    __syncthreads();
    int n = tid;
#pragma unroll 1
    for (int sc = 0; sc < 8; ++sc) {
        float acc[8];
#pragma unroll
        for (int j = 0; j < 8; ++j) acc[j] = 0.f;
        for (int d = 0; d < 128; ++d) {
            float wv = g_wrecA[d * G4 + n];
#pragma unroll
            for (int j = 0; j < 8; ++j) acc[j] += encL[sc * 8 + j][d] * wv;
        }
#pragma unroll
        for (int j = 0; j < 4; ++j) {
            int s2 = sc * 4 + j;
            g_encW2[((size_t)b * G4 + n) * 32 + s2] = packh(acc[2 * j], acc[2 * j + 1]);
        }
    }
    if (tid < 64) {
        for (int o = 0; o < 5; ++o) {
            float acc = 0.f;
            for (int d = 0; d < 128; ++d)
                acc += encL[tid][d] * g_Wao[(128 + d) * 5 + o];
            g_encWao[((size_t)b * 64 + tid) * 5 + o] = acc;
        }
    }
}

// ---- B: pre2 = Arows @ W_ih[0:160]; stores PERMUTED column for kC ----
__global__ void __attribute__((amdgpu_flat_work_group_size(512, 512),
                               amdgpu_waves_per_eu(2, 2)))
kB(const float* __restrict__ Wih) {
    int n = threadIdx.x;
    int m0 = blockIdx.x * 8;
    int pl = ((n & 127) << 2) | (n >> 7);    // kC thread tid=pl has gate n
    float racc[8];
#pragma unroll
    for (int r = 0; r < 8; ++r) racc[r] = 0.0f;
#pragma unroll 1
    for (int pass = 0; pass < 2; ++pass) {
        float wcol[80];
#pragma unroll
        for (int j = 0; j < 80; ++j) wcol[j] = Wih[(pass * 80 + j) * G4 + n];
#pragma unroll
        for (int r = 0; r < 8; ++r) {
            const float4* rp = (const float4*)(g_ArowsF + (size_t)(m0 + r) * KTOP + pass * 80);
            float a0 = 0.f, a1 = 0.f, a2 = 0.f, a3 = 0.f;
#pragma unroll
            for (int q = 0; q < 20; ++q) {
                float4 v = rp[q];
                a0 += wcol[4 * q + 0] * v.x;
                a1 += wcol[4 * q + 1] * v.y;
                a2 += wcol[4 * q + 2] * v.z;
                a3 += wcol[4 * q + 3] * v.w;
            }
            racc[r] += (a0 + a1) + (a2 + a3);
        }
    }
#pragma unroll
    for (int r = 0; r < 8; ++r)
        g_pre2[(size_t)(m0 + r) * G4 + pl] = racc[r];
}

// f16-dot2 consume: uint4 W = 4 f16-pairs vs h-pairs hvals4[jb]; 8 MACs in 4 inst
#define CONS1f(W, jb) { uint4 hp = hvals4[jb]; \
    acc0 = fdot2(W.x, hp.x, acc0); \
    acc1 = fdot2(W.y, hp.y, acc1); \
    acc0 = fdot2(W.z, hp.z, acc0); \
    acc1 = fdot2(W.w, hp.w, acc1); }
#define LDP(R, jb)  R = wp[(jb) * 1024];          // h-half (kh=0), column n

// lgkmcnt-only barrier (round 13): global ops stay in flight across it.
#define SYNC() do { __builtin_amdgcn_sched_barrier(0); \
    asm volatile("s_waitcnt lgkmcnt(0)" ::: "memory"); \
    __builtin_amdgcn_s_barrier(); \
    __builtin_amdgcn_sched_barrier(0); } while (0)

// ---- C: sequential recurrence, 512 threads — 3 barriers/step ----
// Round-19: (a) atth+scores MERGED into one barrier-free phase: every wave's
// lane a computes atth[a] redundantly (operands are LDS broadcasts) and keeps
// it in-register — the scores term tanh(penc[s][a]+atth[a])*wa[a] is
// lane-local; each wave then reduces its 8 score rows via 6-level shfl trees.
// (b) s_h2 DOUBLE-BUFFERED: r15-r18 had a latent cross-wave race (pointwise
// wrote s_h2 in the same barrier interval other waves' dots read it).
// (c) waves_per_eu(2,2) (matches actual residency) for a 256-VGPR budget so
// the 16 persistent weight uint4s stay in registers (r18 crushed to 64 and
// re-loaded from L2 each step).
__global__ void __attribute__((amdgpu_flat_work_group_size(512, 512),
                               amdgpu_waves_per_eu(2, 2)))
kC(const float* __restrict__ Walpha,
   const float* __restrict__ balpha,
   const float* __restrict__ bh2a,
   const float* __restrict__ W2a) {
    __shared__ __align__(16) unsigned int s_h2[2][64]; // h packed f16x2, double-buffered
    __shared__ float s_scores[64];
    __shared__ __align__(16) unsigned int s_wgt2[32];  // wgt packed f16x2
    __shared__ __align__(16) float s_walpha[64];
    __shared__ float s_bh2a[64];
    extern __shared__ __align__(16) char dsm[];
    unsigned int* s_encW  = (unsigned int*)dsm;             // [512][34] u32  69632 B
    float*        s_penc  = (float*)(dsm + 69632);          // [64][65] f32   16640 B
    unsigned int* s_w2aTp = (unsigned int*)(dsm + 69632 + 16640); // [64][66] u32 16896 B

    int tid = threadIdx.x;
    int b = blockIdx.x;
    int lane = tid & 63;
    int qb = lane & ~3;                       // quad base lane
    int n = ((tid & 3) << 7) | (tid >> 2);    // logical gate id
    int m = tid >> 2;                         // h index (0..127)
    int w = tid >> 6;                         // wave id

    // one-time persistent weight load (column n, h-half f16 pairs)
    const uint4* wp = ((const uint4*)g_wpk2) + n;
    uint4 P0,P1,P2,P3,P4,P5,P6,P7,P8,P9,P10,P11,P12,P13,P14,P15;
    LDP(P0,0)  LDP(P1,1)  LDP(P2,2)  LDP(P3,3)
    LDP(P4,4)  LDP(P5,5)  LDP(P6,6)  LDP(P7,7)
    LDP(P8,8)  LDP(P9,9)  LDP(P10,10) LDP(P11,11)
    LDP(P12,12) LDP(P13,13) LDP(P14,14) LDP(P15,15)

    float bias_r = g_bias[n];
    float bc_r   = bias_r + g_c0[n];
    float c_reg  = 0.0f;                      // cell state, in-register (quad-redundant)

    if (tid < 64) { s_h2[0][tid] = 0u; s_walpha[tid] = Walpha[tid]; s_bh2a[tid] = bh2a[tid]; }
    for (int i = tid; i < 16384; i += 512) {        // encW → LDS at PERMUTED loc
        int row = i >> 5, s2 = i & 31;
        int loc = ((row & 127) << 2) | (row >> 7);  // loc(n(tid)) == tid
        s_encW[loc * 34 + s2] = g_encW2[(size_t)b * 16384 + i];
    }
    for (int i = tid; i < 4096; i += 512) {
        int s = i >> 6, a = i & 63;
        s_penc[s * 65 + a] = g_penc[((size_t)b * 64 + s) * 64 + a];
    }
    for (int i = tid; i < 4096; i += 512) {         // W2a^T packed f16 pairs, stride 66
        int a = i & 63, k2 = i >> 6;
        s_w2aTp[a * 66 + k2] = packh(W2a[(2 * k2) * 64 + a], W2a[(2 * k2 + 1) * 64 + a]);
    }
    float bal = balpha[0];

    const float* pre2p = g_pre2 + (size_t)b * TDIM * G4 + tid;   // permuted store → +tid
    float* hwp0 = g_hw + (size_t)b * TDIM * 192;

    for (int t = 0; t < TDIM; ++t) {
        int cur = t & 1, nxt = cur ^ 1;
        SYNC();                          // (1) h(t-1) [buf cur], wgt(t-1) ready
        float pre2v = pre2p[(size_t)t * G4];
        float acc0 = 0.f, acc1 = 0.f;
        const uint4* hvals4 = (const uint4*)(&s_h2[cur][0]);
        CONS1f(P0,0)  CONS1f(P1,1)  CONS1f(P2,2)  CONS1f(P3,3)
        CONS1f(P4,4)  CONS1f(P5,5)  CONS1f(P6,6)  CONS1f(P7,7)
        CONS1f(P8,8)  CONS1f(P9,9)  CONS1f(P10,10) CONS1f(P11,11)
        CONS1f(P12,12) CONS1f(P13,13) CONS1f(P14,14) CONS1f(P15,15)
        float g = acc0 + acc1 + pre2v + (t ? bc_r : bias_r);
        if (t) {                          // wgt-half: 32 dot2 from row tid (conflict-free)
            const uint2* er = (const uint2*)(s_encW + tid * 34);
            const uint2* wg = (const uint2*)s_wgt2;
            float w0 = 0.f, w1 = 0.f;
#pragma unroll
            for (int j = 0; j < 16; ++j) {
                uint2 ew = er[j], ww = wg[j];
                w0 = fdot2(ew.x, ww.x, w0);
                w1 = fdot2(ew.y, ww.y, w1);
            }
            g += w0 + w1;
        }
        // LSTM pointwise IN-QUAD: lanes 4m..4m+3 hold gates (i,f,g,o) of h_m
        {
            float gi = __shfl(g, qb + 0);
            float gf = __shfl(g, qb + 1);
            float gg = __shfl(g, qb + 2);
            float go = __shfl(g, qb + 3);
            float c = sigm(gf) * c_reg + sigm(gi) * tanh_fast(gg);
            c_reg = c;
            float h = sigm(go) * tanh_fast(c);
            if ((tid & 3) == 0) hwp0[(size_t)t * 192 + m] = h;
            float h_p = __shfl(h, lane ^ 4);          // partner quad's h
            if ((tid & 7) == 0) s_h2[nxt][tid >> 3] = packh(h, h_p);  // race-free buf
        }
        SYNC();                          // (2) h(t) ready in buf nxt
        // merged atth+scores: lane a computes atth[a] in-register (redundant
        // per wave), then this wave reduces its 8 score rows via shfl trees
        {
            int a = lane;
            const uint2* hv2 = (const uint2*)(&s_h2[nxt][0]);    // broadcast reads
            const uint2* wr  = (const uint2*)(s_w2aTp + a * 66); // 2-way banks: free
            float a0 = 0.f, a1 = 0.f;
#pragma unroll
            for (int j = 0; j < 16; ++j) {
                uint2 wv = wr[j], hh = hv2[j];
                a0 = fdot2(wv.x, hh.x, a0);
                a1 = fdot2(wv.y, hh.y, a1);
            }
            float atv = a0 + a1 + s_bh2a[a];          // atth[a], lane-local
#pragma unroll
            for (int j = 0; j < 8; ++j) {
                int ss = w * 8 + j;
                float val = tanh_fast(s_penc[ss * 65 + a] + atv) * s_walpha[a];
                val += __shfl_xor(val, 1);
                val += __shfl_xor(val, 2);
                val += __shfl_xor(val, 4);
                val += __shfl_xor(val, 8);
                val += __shfl_xor(val, 16);
                val += __shfl_xor(val, 32);
                if (lane == 0) s_scores[ss] = val + bal;
            }
        }
        SYNC();                          // (3) scores ready
        if (tid < 64) {                  // softmax → wgt packed (+ f32 to g_hw for kD)
            float v = s_scores[tid];
            float mx = v;
#pragma unroll
            for (int off = 32; off > 0; off >>= 1) mx = fmaxf(mx, __shfl_xor(mx, off));
            float e = __expf(v - mx);
            float sum = e;
#pragma unroll
            for (int off = 32; off > 0; off >>= 1) sum += __shfl_xor(sum, off);
            float wv = e / sum;
            hwp0[(size_t)t * 192 + 128 + tid] = wv;
            float w_p = __shfl(wv, lane ^ 1);
            if ((tid & 1) == 0) s_wgt2[tid >> 1] = packh(wv, w_p);
        }
        // loop-top SYNC covers s_wgt2/s_scores reuse
    }
}

// ---- D: out = h@Wao_h + wgt@encWao[b] + bao ----
__global__ void kD(float* __restrict__ out) {
    int r = blockIdx.x * 4 + (threadIdx.x >> 6);
    int lane = threadIdx.x & 63;
    int b = r / TDIM;
    float acc[5] = {0.f, 0.f, 0.f, 0.f, 0.f};
    if (lane < 48) {
        const float4* hv = (const float4*)(g_hw + (size_t)r * 192);
        float4 v = hv[lane];
        int k0 = lane * 4;
        if (lane < 32) {
#pragma unroll
            for (int o = 0; o < 5; ++o)
                acc[o] = v.x * g_Wao[(k0 + 0) * 5 + o] + v.y * g_Wao[(k0 + 1) * 5 + o] +
                         v.z * g_Wao[(k0 + 2) * 5 + o] + v.w * g_Wao[(k0 + 3) * 5 + o];
        } else {
            int s0 = k0 - 128;
            const float* ew = g_encWao + ((size_t)b * 64 + s0) * 5;
#pragma unroll
            for (int o = 0; o < 5; ++o)
                acc[o] = v.x * ew[o] + v.y * ew[5 + o] + v.z * ew[10 + o] + v.w * ew[15 + o];
        }
    }
#pragma unroll
    for (int off = 32; off > 0; off >>= 1) {
#pragma unroll
        for (int o = 0; o < 5; ++o) acc[o] += __shfl_xor(acc[o], off);
    }
    if (lane == 0) {
#pragma unroll
        for (int o = 0; o < 5; ++o) out[(size_t)r * 5 + o] = acc[o] + g_bao[o];
    }
}

extern "C" void kernel_launch(void* const* d_in, const int* in_sizes, int n_in,
                              void* d_out, int out_size, void* d_ws, size_t ws_size,
                              hipStream_t stream) {
    (void)in_sizes; (void)n_in; (void)d_ws; (void)ws_size; (void)out_size;
    const float* tok  = (const float*)d_in[0];
    const float* feat = (const float*)d_in[1];
    const float* FH   = (const float*)d_in[2];
    const float* Wemb = (const float*)d_in[3];
    const float* bemb = (const float*)d_in[4];
    const float* Wih  = (const float*)d_in[5];
    const float* bih  = (const float*)d_in[6];
    const float* Whh  = (const float*)d_in[7];
    const float* bhh  = (const float*)d_in[8];
    const float* W2a  = (const float*)d_in[9];
    const float* bh2a = (const float*)d_in[10];
    const float* Wal  = (const float*)d_in[11];
    const float* bal  = (const float*)d_in[12];
    const float* Wep  = (const float*)d_in[13];
    const float* bep  = (const float*)d_in[14];
    const float* Waap = (const float*)d_in[15];
    const float* baap = (const float*)d_in[16];
    const float* Wout = (const float*)d_in[17];
    const float* bout = (const float*)d_in[18];
    float* out = (float*)d_out;

    const int kc_dyn_lds = 69632 + 16640 + 16896;    // 103168 B
    (void)hipFuncSetAttribute((const void*)kC,
                              hipFuncAttributeMaxDynamicSharedMemorySize,
                              kc_dyn_lds);

    kA1<<<dim3(BT / 4), dim3(256), 0, stream>>>(tok, feat, Wemb, bemb);
    kA2a<<<dim3(128), dim3(512), 0, stream>>>(Wih, Whh, Waap);
    kA2c<<<dim3(1), dim3(512), 0, stream>>>(bih, bhh, Wih, Waap, baap, Wout, bout);
    kA2d<<<dim3(64), dim3(256), 0, stream>>>(FH, Wep, bep);
    kA2e<<<dim3(BDIM), dim3(512), 0, stream>>>(FH);
    kB<<<dim3(BT / 8), dim3(512), 0, stream>>>(Wih);
    kC<<<dim3(64), dim3(512), kc_dyn_lds, stream>>>(Wal, bal, bh2a, W2a);
    kD<<<dim3(BT / 4), dim3(256), 0, stream>>>(out);
}

// Round 20
// 1347.064 us; speedup vs baseline: 1.4118x; 1.4118x over previous
//
#include <hip/hip_runtime.h>
#include <hip/hip_bf16.h>

#define BDIM 64
#define TDIM 360
#define BT (BDIM*TDIM)        // 23040
#define CDIM 128
#define HWSZ 1024
#define SDIM 64
#define G4 512
#define KTOP 160

typedef __hip_bfloat16 bf16;
typedef __fp16 h2 __attribute__((ext_vector_type(2)));   // cvt_pkrtz/fdot2 native type

static __device__ __forceinline__ unsigned int f2bu(float x) {
    bf16 b = __float2bfloat16(x);
    unsigned short u; __builtin_memcpy(&u, &b, 2); return (unsigned int)u;
}
static __device__ __forceinline__ h2 u2h(unsigned int u) {
    h2 r; __builtin_memcpy(&r, &u, 4); return r;
}
static __device__ __forceinline__ unsigned int packh(float a, float b) {
    h2 v = __builtin_amdgcn_cvt_pkrtz(a, b);
    unsigned int u; __builtin_memcpy(&u, &v, 4); return u;
}
static __device__ __forceinline__ float fdot2(unsigned int a, unsigned int b, float c) {
    return __builtin_amdgcn_fdot2(u2h(a), u2h(b), c, false);
}
static __device__ __forceinline__ float tanh_fast(float x) {
    float e = __expf(2.0f * x);
    return 1.0f - 2.0f / (e + 1.0f);
}
static __device__ __forceinline__ float sigm(float x) {
    return 1.0f / (1.0f + __expf(-x));
}

// ---- static device workspace ----
__device__ float        g_ArowsF[BT * KTOP];   // [x_emb(32) | in_seq(128)] fp32
// pre2 stored PERMUTED: column pl = ((n&127)<<2)|(n>>7) so kC reads at +tid
__device__ float        g_pre2[BT * G4];
// folded recurrent weights (h-half), f16 PAIRS, streaming layout
__device__ __align__(16) unsigned int g_wpk2[16 * 1024 * 4];
__device__ float        g_wrecA[128 * G4];     // att-half fold, fp32 (for kA2e)
__device__ __align__(16) unsigned int g_encW2[BDIM * G4 * 32]; // encW[b][n][s2] f16-pairs
__device__ float        g_encWao[BDIM * 64 * 5];
__device__ float        g_penc[BDIM * SDIM * 64];
__device__ float        g_hw[BT * 192];        // [h(128) | wgt(64)] per (b,t)
__device__ float        g_Wao[256 * 5];
__device__ float        g_bao[5];
__device__ float        g_bias[G4];
__device__ float        g_c0[G4];

// ---- A1: build [x_emb | gathered feature] rows ----
__global__ void kA1(const float* __restrict__ tok, const float* __restrict__ feat,
                    const float* __restrict__ Wemb, const float* __restrict__ bemb) {
    int row  = blockIdx.x * 4 + (threadIdx.x >> 6);
    int lane = threadIdx.x & 63;
    const float* tp = tok + (size_t)row * 4;
    float t0 = tp[0], t1 = tp[1], t2 = tp[2], t3 = tp[3];
    int b = row / TDIM;
    int x = (int)(t0 * 100.0f);
    int y = (int)(t1 * 100.0f);
    x = min(max(x, 0), 31);
    y = min(max(y, 0), 31);
    int idx = y * 32 + x;
    float* out = g_ArowsF + (size_t)row * KTOP;
    if (lane < 32) {
        float e = t0 * Wemb[lane] + t1 * Wemb[32 + lane] +
                  t2 * Wemb[64 + lane] + t3 * Wemb[96 + lane] + bemb[lane];
        out[lane] = e;
    }
    const float* fb = feat + (size_t)b * CDIM * HWSZ + idx;
    out[32 + lane]      = fb[(size_t)lane * HWSZ];
    out[32 + 64 + lane] = fb[(size_t)(64 + lane) * HWSZ];
}

// ---- A2a: fold recurrent weights; h-half packed f16, att-half fp32 ----
__global__ void kA2a(const float* __restrict__ Wih, const float* __restrict__ Whh,
                     const float* __restrict__ Waap) {
    __shared__ float sa0[128], sa1[128];
    int p = blockIdx.x, n = threadIdx.x;
    int r0 = 2 * p, r1 = 2 * p + 1;
    if (n < 128)            sa0[n]        = Waap[r0 * 128 + n];
    else if (n < 256)       sa1[n - 128]  = Waap[r1 * 128 + (n - 128)];
    __syncthreads();
    float acc0 = (r0 < 128) ? Whh[r0 * G4 + n] : 0.0f;
    float acc1 = (r1 < 128) ? Whh[r1 * G4 + n] : 0.0f;
    for (int j = 0; j < 128; ++j) {
        float wi = Wih[(160 + j) * G4 + n];
        acc0 += sa0[j] * wi;
        acc1 += sa1[j] * wi;
    }
    int kh = p >> 6, j = p & 63;
    int jblk = j >> 2, jj = j & 3;
    int u = kh * 512 + n;
    g_wpk2[((size_t)jblk * 1024 + u) * 4 + jj] = packh(acc0, acc1);  // f16 pair
    if (p >= 64) {                         // att-half rows, fp32 for kA2e fold
        g_wrecA[(r0 - 128) * G4 + n] = acc0;
        g_wrecA[(r1 - 128) * G4 + n] = acc1;
    }
}

// ---- A2c: bias vectors, c0, Wao, bao ----
__global__ void kA2c(const float* __restrict__ bih, const float* __restrict__ bhh,
                     const float* __restrict__ Wih, const float* __restrict__ Waap,
                     const float* __restrict__ baap, const float* __restrict__ Wout,
                     const float* __restrict__ bout) {
    __shared__ float sb[128];
    int n = threadIdx.x;
    if (n < 128) sb[n] = baap[n];
    __syncthreads();
    g_bias[n] = bih[n] + bhh[n];
    float c0 = 0.0f;
    for (int j = 0; j < 128; ++j) c0 += sb[j] * Wih[(160 + j) * G4 + n];
    g_c0[n] = c0;
    if (n < 256) {
        for (int o = 0; o < 5; ++o) {
            float acc = 0.0f;
            for (int j = 0; j < 128; ++j) acc += Waap[n * 128 + j] * Wout[j * 5 + o];
            g_Wao[n * 5 + o] = acc;
        }
    }
    if (n == 0) {
        for (int o = 0; o < 5; ++o) {
            float acc = bout[o];
            for (int j = 0; j < 128; ++j) acc += sb[j] * Wout[j * 5 + o];
            g_bao[o] = acc;
        }
    }
}

// ---- A2d: p_enc ----
__global__ void kA2d(const float* __restrict__ FH, const float* __restrict__ Wep,
                     const float* __restrict__ bep) {
    __shared__ float sfh[128 * 64];
    int b = blockIdx.x, tid = threadIdx.x;
    for (int i = tid; i < 128 * 64; i += 256) sfh[i] = FH[(size_t)b * 128 * 64 + i];
    __syncthreads();
    int a = tid & 63, sg = tid >> 6;
    float bias = bep[a];
    float acc[16];
#pragma unroll
    for (int i = 0; i < 16; ++i) acc[i] = bias;
    for (int d = 0; d < 128; ++d) {
        float wa = Wep[d * 64 + a];
#pragma unroll
        for (int i = 0; i < 16; ++i) acc[i] += sfh[d * 64 + sg * 16 + i] * wa;
    }
    for (int i = 0; i < 16; ++i)
        g_penc[((size_t)b * 64 + sg * 16 + i) * 64 + a] = acc[i];
}

// ---- A2e: encW[b] = enc[b] @ Wrec_att (f16 pack), encWao[b] = enc[b] @ Wao_att ----
__global__ void kA2e(const float* __restrict__ FH) {
    __shared__ float encL[64][129];      // enc[s][d], padded
    int b = blockIdx.x, tid = threadIdx.x;
    for (int i = tid; i < 8192; i += 512) {
        int d = i >> 6, s = i & 63;
        encL[s][d] = FH[(size_t)b * 8192 + i];
    }
    __syncthreads();
    int n = tid;
#pragma unroll 1
    for (int sc = 0; sc < 8; ++sc) {
        float acc[8];
#pragma unroll
        for (int j = 0; j < 8; ++j) acc[j] = 0.f;
        for (int d = 0; d < 128; ++d) {
            float wv = g_wrecA[d * G4 + n];
#pragma unroll
            for (int j = 0; j < 8; ++j) acc[j] += encL[sc * 8 + j][d] * wv;
        }
#pragma unroll
        for (int j = 0; j < 4; ++j) {
            int s2 = sc * 4 + j;
            g_encW2[((size_t)b * G4 + n) * 32 + s2] = packh(acc[2 * j], acc[2 * j + 1]);
        }
    }
    if (tid < 64) {
        for (int o = 0; o < 5; ++o) {
            float acc = 0.f;
            for (int d = 0; d < 128; ++d)
                acc += encL[tid][d] * g_Wao[(128 + d) * 5 + o];
            g_encWao[((size_t)b * 64 + tid) * 5 + o] = acc;
        }
    }
}

// ---- B: pre2 = Arows @ W_ih[0:160]; stores PERMUTED column for kC ----
__global__ void __attribute__((amdgpu_flat_work_group_size(512, 512),
                               amdgpu_waves_per_eu(2, 2)))
kB(const float* __restrict__ Wih) {
    int n = threadIdx.x;
    int m0 = blockIdx.x * 8;
    int pl = ((n & 127) << 2) | (n >> 7);    // kC thread tid=pl has gate n
    float racc[8];
#pragma unroll
    for (int r = 0; r < 8; ++r) racc[r] = 0.0f;
#pragma unroll 1
    for (int pass = 0; pass < 2; ++pass) {
        float wcol[80];
#pragma unroll
        for (int j = 0; j < 80; ++j) wcol[j] = Wih[(pass * 80 + j) * G4 + n];
#pragma unroll
        for (int r = 0; r < 8; ++r) {
            const float4* rp = (const float4*)(g_ArowsF + (size_t)(m0 + r) * KTOP + pass * 80);
            float a0 = 0.f, a1 = 0.f, a2 = 0.f, a3 = 0.f;
#pragma unroll
            for (int q = 0; q < 20; ++q) {
                float4 v = rp[q];
                a0 += wcol[4 * q + 0] * v.x;
                a1 += wcol[4 * q + 1] * v.y;
                a2 += wcol[4 * q + 2] * v.z;
                a3 += wcol[4 * q + 3] * v.w;
            }
            racc[r] += (a0 + a1) + (a2 + a3);
        }
    }
#pragma unroll
    for (int r = 0; r < 8; ++r)
        g_pre2[(size_t)(m0 + r) * G4 + pl] = racc[r];
}

// f16-dot2 consume: uint4 W = 4 f16-pairs vs h-pairs hvals4[jb]; 8 MACs in 4 inst
#define CONS1f(W, jb) { uint4 hp = hvals4[jb]; \
    acc0 = fdot2(W.x, hp.x, acc0); \
    acc1 = fdot2(W.y, hp.y, acc1); \
    acc0 = fdot2(W.z, hp.z, acc0); \
    acc1 = fdot2(W.w, hp.w, acc1); }
#define LDP(R, jb)  R = wp[(jb) * 1024];          // h-half (kh=0), column n

// lgkmcnt-only barrier (round 13): global ops stay in flight across it.
#define SYNC() do { __builtin_amdgcn_sched_barrier(0); \
    asm volatile("s_waitcnt lgkmcnt(0)" ::: "memory"); \
    __builtin_amdgcn_s_barrier(); \
    __builtin_amdgcn_sched_barrier(0); } while (0)

// ---- C: sequential recurrence, 512 threads — r18 phase structure restored ----
// Round-20: r19's merged atth+scores phase regressed (48 serialized shfl/step
// + 4x-redundant atth >> 1 saved barrier); revert to r18's separate 8-lane
// phases (4 barriers/step, measured 973 us). KEEP from r19: (a) s_h2
// double-buffer (fixes r15-r18's latent cross-wave race), (b)
// waves_per_eu(2,2) for the 256-VGPR budget so the 16 persistent weight
// uint4s stay register-resident (r18's VGPR-64 crush re-loaded them from L2
// every step).
__global__ void __attribute__((amdgpu_flat_work_group_size(512, 512),
                               amdgpu_waves_per_eu(2, 2)))
kC(const float* __restrict__ Walpha,
   const float* __restrict__ balpha,
   const float* __restrict__ bh2a,
   const float* __restrict__ W2a) {
    __shared__ __align__(16) unsigned int s_h2[2][64]; // h packed f16x2, double-buffered
    __shared__ __align__(16) float s_atth[64];
    __shared__ float s_scores[64];
    __shared__ __align__(16) unsigned int s_wgt2[32];  // wgt packed f16x2
    __shared__ __align__(16) float s_walpha[64];
    __shared__ float s_bh2a[64];
    extern __shared__ __align__(16) char dsm[];
    unsigned int* s_encW  = (unsigned int*)dsm;             // [512][34] u32  69632 B
    float*        s_penc  = (float*)(dsm + 69632);          // [64][65] f32   16640 B
    unsigned int* s_w2aTp = (unsigned int*)(dsm + 69632 + 16640); // [64][66] u32 16896 B

    int tid = threadIdx.x;
    int b = blockIdx.x;
    int lane = tid & 63;
    int qb = lane & ~3;                       // quad base lane
    int n = ((tid & 3) << 7) | (tid >> 2);    // logical gate id
    int m = tid >> 2;                         // h index (0..127)

    // one-time persistent weight load (column n, h-half f16 pairs)
    const uint4* wp = ((const uint4*)g_wpk2) + n;
    uint4 P0,P1,P2,P3,P4,P5,P6,P7,P8,P9,P10,P11,P12,P13,P14,P15;
    LDP(P0,0)  LDP(P1,1)  LDP(P2,2)  LDP(P3,3)
    LDP(P4,4)  LDP(P5,5)  LDP(P6,6)  LDP(P7,7)
    LDP(P8,8)  LDP(P9,9)  LDP(P10,10) LDP(P11,11)
    LDP(P12,12) LDP(P13,13) LDP(P14,14) LDP(P15,15)

    float bias_r = g_bias[n];
    float bc_r   = bias_r + g_c0[n];
    float c_reg  = 0.0f;                      // cell state, in-register (quad-redundant)

    if (tid < 64) { s_h2[0][tid] = 0u; s_walpha[tid] = Walpha[tid]; s_bh2a[tid] = bh2a[tid]; }
    for (int i = tid; i < 16384; i += 512) {        // encW → LDS at PERMUTED loc
        int row = i >> 5, s2 = i & 31;
        int loc = ((row & 127) << 2) | (row >> 7);  // loc(n(tid)) == tid
        s_encW[loc * 34 + s2] = g_encW2[(size_t)b * 16384 + i];
    }
    for (int i = tid; i < 4096; i += 512) {
        int s = i >> 6, a = i & 63;
        s_penc[s * 65 + a] = g_penc[((size_t)b * 64 + s) * 64 + a];
    }
    for (int i = tid; i < 4096; i += 512) {         // W2a^T packed f16 pairs, stride 66
        int a = i & 63, k2 = i >> 6;
        s_w2aTp[a * 66 + k2] = packh(W2a[(2 * k2) * 64 + a], W2a[(2 * k2 + 1) * 64 + a]);
    }
    float bal = balpha[0];

    const float* pre2p = g_pre2 + (size_t)b * TDIM * G4 + tid;   // permuted store → +tid
    float* hwp0 = g_hw + (size_t)b * TDIM * 192;

    for (int t = 0; t < TDIM; ++t) {
        int cur = t & 1, nxt = cur ^ 1;
        SYNC();                          // (1) h(t-1) [buf cur], wgt(t-1) ready
        float pre2v = pre2p[(size_t)t * G4];
        float acc0 = 0.f, acc1 = 0.f;
        const uint4* hvals4 = (const uint4*)(&s_h2[cur][0]);
        CONS1f(P0,0)  CONS1f(P1,1)  CONS1f(P2,2)  CONS1f(P3,3)
        CONS1f(P4,4)  CONS1f(P5,5)  CONS1f(P6,6)  CONS1f(P7,7)
        CONS1f(P8,8)  CONS1f(P9,9)  CONS1f(P10,10) CONS1f(P11,11)
        CONS1f(P12,12) CONS1f(P13,13) CONS1f(P14,14) CONS1f(P15,15)
        float g = acc0 + acc1 + pre2v + (t ? bc_r : bias_r);
        if (t) {                          // wgt-half: 32 dot2 from row tid (conflict-free)
            const uint2* er = (const uint2*)(s_encW + tid * 34);
            const uint2* wg = (const uint2*)s_wgt2;
            float w0 = 0.f, w1 = 0.f;
#pragma unroll
            for (int j = 0; j < 16; ++j) {
                uint2 ew = er[j], ww = wg[j];
                w0 = fdot2(ew.x, ww.x, w0);
                w1 = fdot2(ew.y, ww.y, w1);
            }
            g += w0 + w1;
        }
        // LSTM pointwise IN-QUAD: lanes 4m..4m+3 hold gates (i,f,g,o) of h_m
        {
            float gi = __shfl(g, qb + 0);
            float gf = __shfl(g, qb + 1);
            float gg = __shfl(g, qb + 2);
            float go = __shfl(g, qb + 3);
            float c = sigm(gf) * c_reg + sigm(gi) * tanh_fast(gg);
            c_reg = c;
            float h = sigm(go) * tanh_fast(c);
            if ((tid & 3) == 0) hwp0[(size_t)t * 192 + m] = h;
            float h_p = __shfl(h, lane ^ 4);          // partner quad's h
            if ((tid & 7) == 0) s_h2[nxt][tid >> 3] = packh(h, h_p);  // race-free buf
        }
        SYNC();                          // (2) h(t) ready in buf nxt
        // att_h[a] = h @ W2a[:,a] + bh2a[a] : 8-lane group per a, 8 dot2/lane
        {
            int a = tid >> 3, sub = tid & 7;
            const uint4* hv = (const uint4*)(&s_h2[nxt][0]);
            uint4 hA = hv[2 * sub], hB = hv[2 * sub + 1];
            const uint2* wr2 = (const uint2*)(s_w2aTp + a * 66 + 8 * sub);
            uint2 wA0 = wr2[0], wA1 = wr2[1], wB0 = wr2[2], wB1 = wr2[3];
            float a0 = 0.f, a1 = 0.f;
            a0 = fdot2(wA0.x, hA.x, a0);  a1 = fdot2(wA0.y, hA.y, a1);
            a0 = fdot2(wA1.x, hA.z, a0);  a1 = fdot2(wA1.y, hA.w, a1);
            a0 = fdot2(wB0.x, hB.x, a0);  a1 = fdot2(wB0.y, hB.y, a1);
            a0 = fdot2(wB1.x, hB.z, a0);  a1 = fdot2(wB1.y, hB.w, a1);
            float acc = a0 + a1;
            acc += __shfl_xor(acc, 1);
            acc += __shfl_xor(acc, 2);
            acc += __shfl_xor(acc, 4);
            if (sub == 0) s_atth[a] = acc + s_bh2a[a];
        }
        SYNC();                          // (3) atth ready
        // scores[s] = sum_a tanh(p_enc + att_h) * W_alpha : 8 lanes per s
        {
            int ss = tid >> 3, sub = tid & 7;
            float acc = 0.f;
#pragma unroll
            for (int j = 0; j < 8; ++j) {
                int a = sub * 8 + j;
                float xv = s_penc[ss * 65 + a] + s_atth[a];
                acc += tanh_fast(xv) * s_walpha[a];
            }
            acc += __shfl_xor(acc, 1);
            acc += __shfl_xor(acc, 2);
            acc += __shfl_xor(acc, 4);
            if (sub == 0) s_scores[ss] = acc + bal;
        }
        SYNC();                          // (4) scores ready
        if (tid < 64) {                  // softmax → wgt packed (+ f32 to g_hw for kD)
            float v = s_scores[tid];
            float mx = v;
#pragma unroll
            for (int off = 32; off > 0; off >>= 1) mx = fmaxf(mx, __shfl_xor(mx, off));
            float e = __expf(v - mx);
            float sum = e;
#pragma unroll
            for (int off = 32; off > 0; off >>= 1) sum += __shfl_xor(sum, off);
            float wv = e / sum;
            hwp0[(size_t)t * 192 + 128 + tid] = wv;
            float w_p = __shfl(wv, lane ^ 1);
            if ((tid & 1) == 0) s_wgt2[tid >> 1] = packh(wv, w_p);
        }
        // loop-top SYNC covers s_wgt2/s_scores reuse
    }
}

// ---- D: out = h@Wao_h + wgt@encWao[b] + bao ----
__global__ void kD(float* __restrict__ out) {
    int r = blockIdx.x * 4 + (threadIdx.x >> 6);
    int lane = threadIdx.x & 63;
    int b = r / TDIM;
    float acc[5] = {0.f, 0.f, 0.f, 0.f, 0.f};
    if (lane < 48) {
        const float4* hv = (const float4*)(g_hw + (size_t)r * 192);
        float4 v = hv[lane];
        int k0 = lane * 4;
        if (lane < 32) {
#pragma unroll
            for (int o = 0; o < 5; ++o)
                acc[o] = v.x * g_Wao[(k0 + 0) * 5 + o] + v.y * g_Wao[(k0 + 1) * 5 + o] +
                         v.z * g_Wao[(k0 + 2) * 5 + o] + v.w * g_Wao[(k0 + 3) * 5 + o];
        } else {
            int s0 = k0 - 128;
            const float* ew = g_encWao + ((size_t)b * 64 + s0) * 5;
#pragma unroll
            for (int o = 0; o < 5; ++o)
                acc[o] = v.x * ew[o] + v.y * ew[5 + o] + v.z * ew[10 + o] + v.w * ew[15 + o];
        }
    }
#pragma unroll
    for (int off = 32; off > 0; off >>= 1) {
#pragma unroll
        for (int o = 0; o < 5; ++o) acc[o] += __shfl_xor(acc[o], off);
    }
    if (lane == 0) {
#pragma unroll
        for (int o = 0; o < 5; ++o) out[(size_t)r * 5 + o] = acc[o] + g_bao[o];
    }
}

extern "C" void kernel_launch(void* const* d_in, const int* in_sizes, int n_in,
                              void* d_out, int out_size, void* d_ws, size_t ws_size,
                              hipStream_t stream) {
    (void)in_sizes; (void)n_in; (void)d_ws; (void)ws_size; (void)out_size;
    const float* tok  = (const float*)d_in[0];
    const float* feat = (const float*)d_in[1];
    const float* FH   = (const float*)d_in[2];
    const float* Wemb = (const float*)d_in[3];
    const float* bemb = (const float*)d_in[4];
    const float* Wih  = (const float*)d_in[5];
    const float* bih  = (const float*)d_in[6];
    const float* Whh  = (const float*)d_in[7];
    const float* bhh  = (const float*)d_in[8];
    const float* W2a  = (const float*)d_in[9];
    const float* bh2a = (const float*)d_in[10];
    const float* Wal  = (const float*)d_in[11];
    const float* bal  = (const float*)d_in[12];
    const float* Wep  = (const float*)d_in[13];
    const float* bep  = (const float*)d_in[14];
    const float* Waap = (const float*)d_in[15];
    const float* baap = (const float*)d_in[16];
    const float* Wout = (const float*)d_in[17];
    const float* bout = (const float*)d_in[18];
    float* out = (float*)d_out;

    const int kc_dyn_lds = 69632 + 16640 + 16896;    // 103168 B
    (void)hipFuncSetAttribute((const void*)kC,
                              hipFuncAttributeMaxDynamicSharedMemorySize,
                              kc_dyn_lds);

    kA1<<<dim3(BT / 4), dim3(256), 0, stream>>>(tok, feat, Wemb, bemb);
    kA2a<<<dim3(128), dim3(512), 0, stream>>>(Wih, Whh, Waap);
    kA2c<<<dim3(1), dim3(512), 0, stream>>>(bih, bhh, Wih, Waap, baap, Wout, bout);
    kA2d<<<dim3(64), dim3(256), 0, stream>>>(FH, Wep, bep);
    kA2e<<<dim3(BDIM), dim3(512), 0, stream>>>(FH);
    kB<<<dim3(BT / 8), dim3(512), 0, stream>>>(Wih);
    kC<<<dim3(64), dim3(512), kc_dyn_lds, stream>>>(Wal, bal, bh2a, W2a);
    kD<<<dim3(BT / 4), dim3(256), 0, stream>>>(out);
}

// Round 21
// 1324.939 us; speedup vs baseline: 1.4354x; 1.0167x over previous
//
#include <hip/hip_runtime.h>
#include <hip/hip_bf16.h>

#define BDIM 64
#define TDIM 360
#define BT (BDIM*TDIM)        // 23040
#define CDIM 128
#define HWSZ 1024
#define SDIM 64
#define G4 512
#define KTOP 160

typedef __hip_bfloat16 bf16;
typedef __fp16 h2 __attribute__((ext_vector_type(2)));   // cvt_pkrtz/fdot2 native type

static __device__ __forceinline__ unsigned int f2bu(float x) {
    bf16 b = __float2bfloat16(x);
    unsigned short u; __builtin_memcpy(&u, &b, 2); return (unsigned int)u;
}
static __device__ __forceinline__ h2 u2h(unsigned int u) {
    h2 r; __builtin_memcpy(&r, &u, 4); return r;
}
static __device__ __forceinline__ unsigned int packh(float a, float b) {
    h2 v = __builtin_amdgcn_cvt_pkrtz(a, b);
    unsigned int u; __builtin_memcpy(&u, &v, 4); return u;
}
static __device__ __forceinline__ float fdot2(unsigned int a, unsigned int b, float c) {
    return __builtin_amdgcn_fdot2(u2h(a), u2h(b), c, false);
}
static __device__ __forceinline__ float tanh_fast(float x) {
    float e = __expf(2.0f * x);
    return 1.0f - 2.0f / (e + 1.0f);
}
static __device__ __forceinline__ float sigm(float x) {
    return 1.0f / (1.0f + __expf(-x));
}

// ---- static device workspace ----
__device__ float        g_ArowsF[BT * KTOP];   // [x_emb(32) | in_seq(128)] fp32
// pre2 stored PERMUTED: column pl = ((n&127)<<2)|(n>>7) so kC reads at +tid
__device__ float        g_pre2[BT * G4];
// folded recurrent weights (h-half), f16 PAIRS, streaming layout
__device__ __align__(16) unsigned int g_wpk2[16 * 1024 * 4];
__device__ float        g_wrecA[128 * G4];     // att-half fold, fp32 (for kA2e)
__device__ __align__(16) unsigned int g_encW2[BDIM * G4 * 32]; // encW[b][n][s2] f16-pairs
__device__ float        g_encWao[BDIM * 64 * 5];
__device__ float        g_penc[BDIM * SDIM * 64];
__device__ float        g_hw[BT * 192];        // [h(128) | wgt(64)] per (b,t)
__device__ float        g_Wao[256 * 5];
__device__ float        g_bao[5];
__device__ float        g_bias[G4];
__device__ float        g_c0[G4];

// ---- A1: build [x_emb | gathered feature] rows ----
__global__ void kA1(const float* __restrict__ tok, const float* __restrict__ feat,
                    const float* __restrict__ Wemb, const float* __restrict__ bemb) {
    int row  = blockIdx.x * 4 + (threadIdx.x >> 6);
    int lane = threadIdx.x & 63;
    const float* tp = tok + (size_t)row * 4;
    float t0 = tp[0], t1 = tp[1], t2 = tp[2], t3 = tp[3];
    int b = row / TDIM;
    int x = (int)(t0 * 100.0f);
    int y = (int)(t1 * 100.0f);
    x = min(max(x, 0), 31);
    y = min(max(y, 0), 31);
    int idx = y * 32 + x;
    float* out = g_ArowsF + (size_t)row * KTOP;
    if (lane < 32) {
        float e = t0 * Wemb[lane] + t1 * Wemb[32 + lane] +
                  t2 * Wemb[64 + lane] + t3 * Wemb[96 + lane] + bemb[lane];
        out[lane] = e;
    }
    const float* fb = feat + (size_t)b * CDIM * HWSZ + idx;
    out[32 + lane]      = fb[(size_t)lane * HWSZ];
    out[32 + 64 + lane] = fb[(size_t)(64 + lane) * HWSZ];
}

// ---- A2a: fold recurrent weights; h-half packed f16, att-half fp32 ----
__global__ void kA2a(const float* __restrict__ Wih, const float* __restrict__ Whh,
                     const float* __restrict__ Waap) {
    __shared__ float sa0[128], sa1[128];
    int p = blockIdx.x, n = threadIdx.x;
    int r0 = 2 * p, r1 = 2 * p + 1;
    if (n < 128)            sa0[n]        = Waap[r0 * 128 + n];
    else if (n < 256)       sa1[n - 128]  = Waap[r1 * 128 + (n - 128)];
    __syncthreads();
    float acc0 = (r0 < 128) ? Whh[r0 * G4 + n] : 0.0f;
    float acc1 = (r1 < 128) ? Whh[r1 * G4 + n] : 0.0f;
    for (int j = 0; j < 128; ++j) {
        float wi = Wih[(160 + j) * G4 + n];
        acc0 += sa0[j] * wi;
        acc1 += sa1[j] * wi;
    }
    int kh = p >> 6, j = p & 63;
    int jblk = j >> 2, jj = j & 3;
    int u = kh * 512 + n;
    g_wpk2[((size_t)jblk * 1024 + u) * 4 + jj] = packh(acc0, acc1);  // f16 pair
    if (p >= 64) {                         // att-half rows, fp32 for kA2e fold
        g_wrecA[(r0 - 128) * G4 + n] = acc0;
        g_wrecA[(r1 - 128) * G4 + n] = acc1;
    }
}

// ---- A2c: bias vectors, c0, Wao, bao ----
__global__ void kA2c(const float* __restrict__ bih, const float* __restrict__ bhh,
                     const float* __restrict__ Wih, const float* __restrict__ Waap,
                     const float* __restrict__ baap, const float* __restrict__ Wout,
                     const float* __restrict__ bout) {
    __shared__ float sb[128];
    int n = threadIdx.x;
    if (n < 128) sb[n] = baap[n];
    __syncthreads();
    g_bias[n] = bih[n] + bhh[n];
    float c0 = 0.0f;
    for (int j = 0; j < 128; ++j) c0 += sb[j] * Wih[(160 + j) * G4 + n];
    g_c0[n] = c0;
    if (n < 256) {
        for (int o = 0; o < 5; ++o) {
            float acc = 0.0f;
            for (int j = 0; j < 128; ++j) acc += Waap[n * 128 + j] * Wout[j * 5 + o];
            g_Wao[n * 5 + o] = acc;
        }
    }
    if (n == 0) {
        for (int o = 0; o < 5; ++o) {
            float acc = bout[o];
            for (int j = 0; j < 128; ++j) acc += sb[j] * Wout[j * 5 + o];
            g_bao[o] = acc;
        }
    }
}

// ---- A2d: p_enc ----
__global__ void kA2d(const float* __restrict__ FH, const float* __restrict__ Wep,
                     const float* __restrict__ bep) {
    __shared__ float sfh[128 * 64];
    int b = blockIdx.x, tid = threadIdx.x;
    for (int i = tid; i < 128 * 64; i += 256) sfh[i] = FH[(size_t)b * 128 * 64 + i];
    __syncthreads();
    int a = tid & 63, sg = tid >> 6;
    float bias = bep[a];
    float acc[16];
#pragma unroll
    for (int i = 0; i < 16; ++i) acc[i] = bias;
    for (int d = 0; d < 128; ++d) {
        float wa = Wep[d * 64 + a];
#pragma unroll
        for (int i = 0; i < 16; ++i) acc[i] += sfh[d * 64 + sg * 16 + i] * wa;
    }
    for (int i = 0; i < 16; ++i)
        g_penc[((size_t)b * 64 + sg * 16 + i) * 64 + a] = acc[i];
}

// ---- A2e: encW[b] = enc[b] @ Wrec_att (f16 pack), encWao[b] = enc[b] @ Wao_att ----
__global__ void kA2e(const float* __restrict__ FH) {
    __shared__ float encL[64][129];      // enc[s][d], padded
    int b = blockIdx.x, tid = threadIdx.x;
    for (int i = tid; i < 8192; i += 512) {
        int d = i >> 6, s = i & 63;
        encL[s][d] = FH[(size_t)b * 8192 + i];
    }
    __syncthreads();
    int n = tid;
#pragma unroll 1
    for (int sc = 0; sc < 8; ++sc) {
        float acc[8];
#pragma unroll
        for (int j = 0; j < 8; ++j) acc[j] = 0.f;
        for (int d = 0; d < 128; ++d) {
            float wv = g_wrecA[d * G4 + n];
#pragma unroll
            for (int j = 0; j < 8; ++j) acc[j] += encL[sc * 8 + j][d] * wv;
        }
#pragma unroll
        for (int j = 0; j < 4; ++j) {
            int s2 = sc * 4 + j;
            g_encW2[((size_t)b * G4 + n) * 32 + s2] = packh(acc[2 * j], acc[2 * j + 1]);
        }
    }
    if (tid < 64) {
        for (int o = 0; o < 5; ++o) {
            float acc = 0.f;
            for (int d = 0; d < 128; ++d)
                acc += encL[tid][d] * g_Wao[(128 + d) * 5 + o];
            g_encWao[((size_t)b * 64 + tid) * 5 + o] = acc;
        }
    }
}

// ---- B: pre2 = Arows @ W_ih[0:160]; stores PERMUTED column for kC ----
__global__ void __attribute__((amdgpu_flat_work_group_size(512, 512),
                               amdgpu_waves_per_eu(2, 2)))
kB(const float* __restrict__ Wih) {
    int n = threadIdx.x;
    int m0 = blockIdx.x * 8;
    int pl = ((n & 127) << 2) | (n >> 7);    // kC thread tid=pl has gate n
    float racc[8];
#pragma unroll
    for (int r = 0; r < 8; ++r) racc[r] = 0.0f;
#pragma unroll 1
    for (int pass = 0; pass < 2; ++pass) {
        float wcol[80];
#pragma unroll
        for (int j = 0; j < 80; ++j) wcol[j] = Wih[(pass * 80 + j) * G4 + n];
#pragma unroll
        for (int r = 0; r < 8; ++r) {
            const float4* rp = (const float4*)(g_ArowsF + (size_t)(m0 + r) * KTOP + pass * 80);
            float a0 = 0.f, a1 = 0.f, a2 = 0.f, a3 = 0.f;
#pragma unroll
            for (int q = 0; q < 20; ++q) {
                float4 v = rp[q];
                a0 += wcol[4 * q + 0] * v.x;
                a1 += wcol[4 * q + 1] * v.y;
                a2 += wcol[4 * q + 2] * v.z;
                a3 += wcol[4 * q + 3] * v.w;
            }
            racc[r] += (a0 + a1) + (a2 + a3);
        }
    }
#pragma unroll
    for (int r = 0; r < 8; ++r)
        g_pre2[(size_t)(m0 + r) * G4 + pl] = racc[r];
}

// f16-dot2 consume: uint4 W = 4 f16-pairs vs h-pairs hvals4[jb]; 8 MACs in 4 inst
#define CONS1f(W, jb) { uint4 hp = hvals4[jb]; \
    acc0 = fdot2(W.x, hp.x, acc0); \
    acc1 = fdot2(W.y, hp.y, acc1); \
    acc0 = fdot2(W.z, hp.z, acc0); \
    acc1 = fdot2(W.w, hp.w, acc1); }
#define LDP(R, jb)  R = wp[(jb) * 1024];          // h-half (kh=0), column n

// lgkmcnt-only barrier (round 13): global ops stay in flight across it.
#define SYNC() do { __builtin_amdgcn_sched_barrier(0); \
    asm volatile("s_waitcnt lgkmcnt(0)" ::: "memory"); \
    __builtin_amdgcn_s_barrier(); \
    __builtin_amdgcn_sched_barrier(0); } while (0)

// ---- C: sequential recurrence, 512 threads — softmax hidden under h-dot ----
// Round-21: dependency analysis — gates(t) = h-dot(h(t-1)) + wgt-dot(wgt(t-1));
// the h-dot doesn't need wgt. So softmax(t-1) moves to the START of step t,
// run by wave 0 while all waves do the h-dot; s_wgt2 is consumed only after
// the following barrier. The ~450-cyc serial softmax chain (12 dependent
// shuffles) hides under ~300 cyc of dot work instead of stalling all 8 waves.
// Also: pre2 is register-double-buffered (load t+1 during step t) to cover
// its ~400-cyc L3 latency (26 MB/dispatch FETCH = L2-missing every step).
// Same arithmetic, same 4 barriers; epilogue computes softmax(359).
__global__ void __attribute__((amdgpu_flat_work_group_size(512, 512),
                               amdgpu_waves_per_eu(2, 2)))
kC(const float* __restrict__ Walpha,
   const float* __restrict__ balpha,
   const float* __restrict__ bh2a,
   const float* __restrict__ W2a) {
    __shared__ __align__(16) unsigned int s_h2[2][64]; // h packed f16x2, double-buffered
    __shared__ __align__(16) float s_atth[64];
    __shared__ float s_scores[64];
    __shared__ __align__(16) unsigned int s_wgt2[32];  // wgt packed f16x2
    __shared__ __align__(16) float s_walpha[64];
    __shared__ float s_bh2a[64];
    extern __shared__ __align__(16) char dsm[];
    unsigned int* s_encW  = (unsigned int*)dsm;             // [512][34] u32  69632 B
    float*        s_penc  = (float*)(dsm + 69632);          // [64][65] f32   16640 B
    unsigned int* s_w2aTp = (unsigned int*)(dsm + 69632 + 16640); // [64][66] u32 16896 B

    int tid = threadIdx.x;
    int b = blockIdx.x;
    int lane = tid & 63;
    int qb = lane & ~3;                       // quad base lane
    int n = ((tid & 3) << 7) | (tid >> 2);    // logical gate id
    int m = tid >> 2;                         // h index (0..127)

    // one-time persistent weight load (column n, h-half f16 pairs)
    const uint4* wp = ((const uint4*)g_wpk2) + n;
    uint4 P0,P1,P2,P3,P4,P5,P6,P7,P8,P9,P10,P11,P12,P13,P14,P15;
    LDP(P0,0)  LDP(P1,1)  LDP(P2,2)  LDP(P3,3)
    LDP(P4,4)  LDP(P5,5)  LDP(P6,6)  LDP(P7,7)
    LDP(P8,8)  LDP(P9,9)  LDP(P10,10) LDP(P11,11)
    LDP(P12,12) LDP(P13,13) LDP(P14,14) LDP(P15,15)

    float bias_r = g_bias[n];
    float bc_r   = bias_r + g_c0[n];
    float c_reg  = 0.0f;                      // cell state, in-register (quad-redundant)

    if (tid < 64) { s_h2[0][tid] = 0u; s_walpha[tid] = Walpha[tid]; s_bh2a[tid] = bh2a[tid]; }
    for (int i = tid; i < 16384; i += 512) {        // encW → LDS at PERMUTED loc
        int row = i >> 5, s2 = i & 31;
        int loc = ((row & 127) << 2) | (row >> 7);  // loc(n(tid)) == tid
        s_encW[loc * 34 + s2] = g_encW2[(size_t)b * 16384 + i];
    }
    for (int i = tid; i < 4096; i += 512) {
        int s = i >> 6, a = i & 63;
        s_penc[s * 65 + a] = g_penc[((size_t)b * 64 + s) * 64 + a];
    }
    for (int i = tid; i < 4096; i += 512) {         // W2a^T packed f16 pairs, stride 66
        int a = i & 63, k2 = i >> 6;
        s_w2aTp[a * 66 + k2] = packh(W2a[(2 * k2) * 64 + a], W2a[(2 * k2 + 1) * 64 + a]);
    }
    float bal = balpha[0];

    const float* pre2p = g_pre2 + (size_t)b * TDIM * G4 + tid;   // permuted store → +tid
    float* hwp0 = g_hw + (size_t)b * TDIM * 192;

    float pre2v = pre2p[0];                    // t=0 prefetched before loop

    for (int t = 0; t < TDIM; ++t) {
        int cur = t & 1, nxt = cur ^ 1;
        SYNC();                          // (1) h(t-1) [buf cur], scores(t-1) ready
        // wave 0: softmax(t-1) → s_wgt2 + g_hw, overlapped with all waves' h-dot
        if (t && tid < 64) {
            float v = s_scores[tid];
            float mx = v;
#pragma unroll
            for (int off = 32; off > 0; off >>= 1) mx = fmaxf(mx, __shfl_xor(mx, off));
            float e = __expf(v - mx);
            float sum = e;
#pragma unroll
            for (int off = 32; off > 0; off >>= 1) sum += __shfl_xor(sum, off);
            float wv = e / sum;
            hwp0[(size_t)(t - 1) * 192 + 128 + tid] = wv;
            float w_p = __shfl(wv, lane ^ 1);
            if ((tid & 1) == 0) s_wgt2[tid >> 1] = packh(wv, w_p);
        }
        float acc0 = 0.f, acc1 = 0.f;
        const uint4* hvals4 = (const uint4*)(&s_h2[cur][0]);
        CONS1f(P0,0)  CONS1f(P1,1)  CONS1f(P2,2)  CONS1f(P3,3)
        CONS1f(P4,4)  CONS1f(P5,5)  CONS1f(P6,6)  CONS1f(P7,7)
        CONS1f(P8,8)  CONS1f(P9,9)  CONS1f(P10,10) CONS1f(P11,11)
        CONS1f(P12,12) CONS1f(P13,13) CONS1f(P14,14) CONS1f(P15,15)
        // prefetch pre2 for t+1 (consumed next step; full step of latency cover)
        int tnn = (t + 1 < TDIM) ? (t + 1) : t;
        float pre2v_next = pre2p[(size_t)tnn * G4];
        SYNC();                          // (2) wgt(t-1) ready
        float g = acc0 + acc1 + pre2v + (t ? bc_r : bias_r);
        if (t) {                          // wgt-half: 32 dot2 from row tid (conflict-free)
            const uint2* er = (const uint2*)(s_encW + tid * 34);
            const uint2* wg = (const uint2*)s_wgt2;
            float w0 = 0.f, w1 = 0.f;
#pragma unroll
            for (int j = 0; j < 16; ++j) {
                uint2 ew = er[j], ww = wg[j];
                w0 = fdot2(ew.x, ww.x, w0);
                w1 = fdot2(ew.y, ww.y, w1);
            }
            g += w0 + w1;
        }
        pre2v = pre2v_next;
        // LSTM pointwise IN-QUAD: lanes 4m..4m+3 hold gates (i,f,g,o) of h_m
        {
            float gi = __shfl(g, qb + 0);
            float gf = __shfl(g, qb + 1);
            float gg = __shfl(g, qb + 2);
            float go = __shfl(g, qb + 3);
            float c = sigm(gf) * c_reg + sigm(gi) * tanh_fast(gg);
            c_reg = c;
            float h = sigm(go) * tanh_fast(c);
            if ((tid & 3) == 0) hwp0[(size_t)t * 192 + m] = h;
            float h_p = __shfl(h, lane ^ 4);          // partner quad's h
            if ((tid & 7) == 0) s_h2[nxt][tid >> 3] = packh(h, h_p);  // race-free buf
        }
        SYNC();                          // (3) h(t) ready in buf nxt
        // att_h[a] = h @ W2a[:,a] + bh2a[a] : 8-lane group per a, 8 dot2/lane
        {
            int a = tid >> 3, sub = tid & 7;
            const uint4* hv = (const uint4*)(&s_h2[nxt][0]);
            uint4 hA = hv[2 * sub], hB = hv[2 * sub + 1];
            const uint2* wr2 = (const uint2*)(s_w2aTp + a * 66 + 8 * sub);
            uint2 wA0 = wr2[0], wA1 = wr2[1], wB0 = wr2[2], wB1 = wr2[3];
            float a0 = 0.f, a1 = 0.f;
            a0 = fdot2(wA0.x, hA.x, a0);  a1 = fdot2(wA0.y, hA.y, a1);
            a0 = fdot2(wA1.x, hA.z, a0);  a1 = fdot2(wA1.y, hA.w, a1);
            a0 = fdot2(wB0.x, hB.x, a0);  a1 = fdot2(wB0.y, hB.y, a1);
            a0 = fdot2(wB1.x, hB.z, a0);  a1 = fdot2(wB1.y, hB.w, a1);
            float acc = a0 + a1;
            acc += __shfl_xor(acc, 1);
            acc += __shfl_xor(acc, 2);
            acc += __shfl_xor(acc, 4);
            if (sub == 0) s_atth[a] = acc + s_bh2a[a];
        }
        SYNC();                          // (4) atth ready
        // scores[s] = sum_a tanh(p_enc + att_h) * W_alpha : 8 lanes per s
        {
            int ss = tid >> 3, sub = tid & 7;
            float acc = 0.f;
#pragma unroll
            for (int j = 0; j < 8; ++j) {
                int a = sub * 8 + j;
                float xv = s_penc[ss * 65 + a] + s_atth[a];
                acc += tanh_fast(xv) * s_walpha[a];
            }
            acc += __shfl_xor(acc, 1);
            acc += __shfl_xor(acc, 2);
            acc += __shfl_xor(acc, 4);
            if (sub == 0) s_scores[ss] = acc + bal;
        }
        // loop-top SYNC(1) publishes scores; softmax runs next iteration
    }
    SYNC();                              // final scores(359) ready
    if (tid < 64) {                      // epilogue softmax(359) → g_hw only
        float v = s_scores[tid];
        float mx = v;
#pragma unroll
        for (int off = 32; off > 0; off >>= 1) mx = fmaxf(mx, __shfl_xor(mx, off));
        float e = __expf(v - mx);
        float sum = e;
#pragma unroll
        for (int off = 32; off > 0; off >>= 1) sum += __shfl_xor(sum, off);
        hwp0[(size_t)(TDIM - 1) * 192 + 128 + tid] = e / sum;
    }
}

// ---- D: out = h@Wao_h + wgt@encWao[b] + bao ----
__global__ void kD(float* __restrict__ out) {
    int r = blockIdx.x * 4 + (threadIdx.x >> 6);
    int lane = threadIdx.x & 63;
    int b = r / TDIM;
    float acc[5] = {0.f, 0.f, 0.f, 0.f, 0.f};
    if (lane < 48) {
        const float4* hv = (const float4*)(g_hw + (size_t)r * 192);
        float4 v = hv[lane];
        int k0 = lane * 4;
        if (lane < 32) {
#pragma unroll
            for (int o = 0; o < 5; ++o)
                acc[o] = v.x * g_Wao[(k0 + 0) * 5 + o] + v.y * g_Wao[(k0 + 1) * 5 + o] +
                         v.z * g_Wao[(k0 + 2) * 5 + o] + v.w * g_Wao[(k0 + 3) * 5 + o];
        } else {
            int s0 = k0 - 128;
            const float* ew = g_encWao + ((size_t)b * 64 + s0) * 5;
#pragma unroll
            for (int o = 0; o < 5; ++o)
                acc[o] = v.x * ew[o] + v.y * ew[5 + o] + v.z * ew[10 + o] + v.w * ew[15 + o];
        }
    }
#pragma unroll
    for (int off = 32; off > 0; off >>= 1) {
#pragma unroll
        for (int o = 0; o < 5; ++o) acc[o] += __shfl_xor(acc[o], off);
    }
    if (lane == 0) {
#pragma unroll
        for (int o = 0; o < 5; ++o) out[(size_t)r * 5 + o] = acc[o] + g_bao[o];
    }
}

extern "C" void kernel_launch(void* const* d_in, const int* in_sizes, int n_in,
                              void* d_out, int out_size, void* d_ws, size_t ws_size,
                              hipStream_t stream) {
    (void)in_sizes; (void)n_in; (void)d_ws; (void)ws_size; (void)out_size;
    const float* tok  = (const float*)d_in[0];
    const float* feat = (const float*)d_in[1];
    const float* FH   = (const float*)d_in[2];
    const float* Wemb = (const float*)d_in[3];
    const float* bemb = (const float*)d_in[4];
    const float* Wih  = (const float*)d_in[5];
    const float* bih  = (const float*)d_in[6];
    const float* Whh  = (const float*)d_in[7];
    const float* bhh  = (const float*)d_in[8];
    const float* W2a  = (const float*)d_in[9];
    const float* bh2a = (const float*)d_in[10];
    const float* Wal  = (const float*)d_in[11];
    const float* bal  = (const float*)d_in[12];
    const float* Wep  = (const float*)d_in[13];
    const float* bep  = (const float*)d_in[14];
    const float* Waap = (const float*)d_in[15];
    const float* baap = (const float*)d_in[16];
    const float* Wout = (const float*)d_in[17];
    const float* bout = (const float*)d_in[18];
    float* out = (float*)d_out;

    const int kc_dyn_lds = 69632 + 16640 + 16896;    // 103168 B
    (void)hipFuncSetAttribute((const void*)kC,
                              hipFuncAttributeMaxDynamicSharedMemorySize,
                              kc_dyn_lds);

    kA1<<<dim3(BT / 4), dim3(256), 0, stream>>>(tok, feat, Wemb, bemb);
    kA2a<<<dim3(128), dim3(512), 0, stream>>>(Wih, Whh, Waap);
    kA2c<<<dim3(1), dim3(512), 0, stream>>>(bih, bhh, Wih, Waap, baap, Wout, bout);
    kA2d<<<dim3(64), dim3(256), 0, stream>>>(FH, Wep, bep);
    kA2e<<<dim3(BDIM), dim3(512), 0, stream>>>(FH);
    kB<<<dim3(BT / 8), dim3(512), 0, stream>>>(Wih);
    kC<<<dim3(64), dim3(512), kc_dyn_lds, stream>>>(Wal, bal, bh2a, W2a);
    kD<<<dim3(BT / 4), dim3(256), 0, stream>>>(out);
}